// Round 4
// baseline (603.175 us; speedup 1.0000x reference)
//
#include <hip/hip_runtime.h>
#include <stdint.h>

#define BATCH 16
#define CH    256
#define CQ    32
#define NPIX  4096

typedef float f32x4 __attribute__((ext_vector_type(4)));
typedef short s16x8 __attribute__((ext_vector_type(8)));

__device__ __forceinline__ ushort f2bf(float f){
  union { float f; uint32_t u; } a; a.f = f;
  uint32_t r = a.u + 0x7FFFu + ((a.u >> 16) & 1u);
  return (ushort)(r >> 16);
}
__device__ __forceinline__ float bf2f(ushort h){
  union { float f; uint32_t u; } a; a.u = ((uint32_t)h) << 16; return a.f;
}
// async global->LDS, 16B per lane; LDS dest = wave-uniform base + lane*16
__device__ __forceinline__ void gload16(const void* g, void* l){
  __builtin_amdgcn_global_load_lds(
      (const __attribute__((address_space(1))) uint32_t*)g,
      (__attribute__((address_space(3))) uint32_t*)l, 16, 0, 0);
}

// ------------------------------------------------------------------
// Projection kernel: q/k/v = W @ x + b (1x1 conv). fp32 VALU.
// Outputs: qhi/qlo/khi/klo [B][N][32] bf16 (hi/lo split),
//          vt [B][C][N] bf16 (transposed, attention A-operand layout).
// ------------------------------------------------------------------
__global__ __launch_bounds__(256) void proj_kernel(
    const float* __restrict__ x,
    const float* __restrict__ Wq, const float* __restrict__ bq,
    const float* __restrict__ Wk, const float* __restrict__ bk,
    const float* __restrict__ Wv, const float* __restrict__ bv,
    ushort* __restrict__ qhi, ushort* __restrict__ qlo,
    ushort* __restrict__ khi, ushort* __restrict__ klo,
    ushort* __restrict__ vt)
{
  // [c][n] layout, stride 65: scalar reads bank (c+n)%32 -> 2-way (free).
  __shared__ float xT[CH][65];   // 66.56 KB -> 2 blocks/CU
  const int b  = blockIdx.y;
  const int n0 = blockIdx.x * 64;
  const int t  = threadIdx.x;
  const float* xb = x + ((size_t)b*CH)*NPIX + n0;

  #pragma unroll
  for (int cc = 0; cc < 16; ++cc) {
    int c  = cc*16 + (t>>4);
    int nb = (t&15)*4;
    float4 v4 = *(const float4*)(xb + (size_t)c*NPIX + nb);
    xT[c][nb+0] = v4.x; xT[c][nb+1] = v4.y;
    xT[c][nb+2] = v4.z; xT[c][nb+3] = v4.w;
  }
  __syncthreads();

  const int n  = t & 63;
  const int wu = __builtin_amdgcn_readfirstlane(t >> 6);  // wave id, uniform

  // ---- q and k: wave owns co = wu*8 .. +7 (W rows wave-uniform -> s_loads)
  {
    const int co0 = wu*8;
    float aq[8], ak[8];
    #pragma unroll
    for (int j2=0;j2<8;++j2){ aq[j2]=bq[co0+j2]; ak[j2]=bk[co0+j2]; }
    #pragma unroll 4
    for (int c=0; c<CH; ++c){
      float xs = xT[c][n];
      #pragma unroll
      for (int j2=0;j2<8;++j2){
        aq[j2] = fmaf(Wq[(co0+j2)*CH+c], xs, aq[j2]);
        ak[j2] = fmaf(Wk[(co0+j2)*CH+c], xs, ak[j2]);
      }
    }
    union { ushort u[8]; uint4 v; } ph, pl;
    size_t row = ((size_t)b*NPIX + n0 + n)*CQ + co0;
    #pragma unroll
    for (int j2=0;j2<8;++j2){
      ushort h = f2bf(aq[j2]); ph.u[j2]=h; pl.u[j2]=f2bf(aq[j2]-bf2f(h));
    }
    *(uint4*)(qhi+row) = ph.v; *(uint4*)(qlo+row) = pl.v;
    #pragma unroll
    for (int j2=0;j2<8;++j2){
      ushort h = f2bf(ak[j2]); ph.u[j2]=h; pl.u[j2]=f2bf(ak[j2]-bf2f(h));
    }
    *(uint4*)(khi+row) = ph.v; *(uint4*)(klo+row) = pl.v;
  }

  // ---- v: wave owns co = wu*64 .. +63, in chunks of 8
  for (int ch2=0; ch2<8; ++ch2){
    const int co0 = wu*64 + ch2*8;
    float av[8];
    #pragma unroll
    for (int j2=0;j2<8;++j2) av[j2]=bv[co0+j2];
    #pragma unroll 4
    for (int c=0; c<CH; ++c){
      float xs = xT[c][n];
      #pragma unroll
      for (int j2=0;j2<8;++j2)
        av[j2] = fmaf(Wv[(co0+j2)*CH+c], xs, av[j2]);
    }
    #pragma unroll
    for (int j2=0;j2<8;++j2)
      vt[((size_t)b*CH + co0+j2)*NPIX + n0 + n] = f2bf(av[j2]);
  }
}

// ------------------------------------------------------------------
// Fused flash attention + residual.
// 256 thr (4 waves), QBLK=128 (32 i/wave), KBLK=64, 2 blocks/CU.
// Swapped MFMAs: S^T = K.Q^T (3-term bf16 hi/lo split), out^T = V^T.P^T.
// V staged to LDS via global_load_lds w/ pre-swizzled source (m97+m173).
// ------------------------------------------------------------------
__global__ __launch_bounds__(256,2) void attn_kernel(
    const ushort* __restrict__ qhi, const ushort* __restrict__ qlo,
    const ushort* __restrict__ khi, const ushort* __restrict__ klo,
    const ushort* __restrict__ vt,  const float* __restrict__ x,
    const float* __restrict__ gamma, float* __restrict__ out)
{
  __shared__ __align__(16) ushort vtile[2][CH*64];  // 64 KB, chunk-XOR swizzled
  __shared__ __align__(16) ushort ptile[4][32*64];  // 16 KB, wave-private

  // T1: XCD-aware swizzle. 512 blocks, 8 XCDs -> each XCD owns 2 batches,
  // so K (1MB) + V stream of those batches stay in its 4MB L2.
  const int flat = blockIdx.x + (int)gridDim.x * blockIdx.y;  // 0..511
  const int nf   = (flat & 7)*64 + (flat >> 3);               // bijective
  const int b    = nf >> 5;
  const int i0   = (nf & 31) << 7;

  const int t   = threadIdx.x;
  const int wu  = __builtin_amdgcn_readfirstlane(t >> 6);
  const int l   = t & 63, lhi = l >> 4, llo = l & 15;

  // V staging: lane l of call k fills LDS row c = wu*64+k*8+(l>>3), phys
  // chunk (l&7). Pre-swizzle source so phys chunk p holds logical chunk
  // p^(c&7)  (c&7 == l>>3 here).
  const int crow = l >> 3;
  const int jsw  = ((l & 7) ^ crow) * 8;
  const uint32_t vbase = (uint32_t)((b*CH + wu*64 + crow)*NPIX) + (uint32_t)jsw;

  // Q fragments (B-operand): lane holds col i = llo, k = lhi*8+e
  s16x8 qh[2], qlf[2];
  #pragma unroll
  for (int rt=0; rt<2; ++rt){
    size_t off = ((size_t)b*NPIX + i0 + wu*32 + rt*16 + llo)*CQ + lhi*8;
    qh[rt]  = *(const s16x8*)(qhi + off);
    qlf[rt] = *(const s16x8*)(qlo + off);
  }

  f32x4 acc[16][2];
  #pragma unroll
  for (int ct=0;ct<16;++ct){
    acc[ct][0] = (f32x4){0.f,0.f,0.f,0.f};
    acc[ct][1] = (f32x4){0.f,0.f,0.f,0.f};
  }
  float m0=-1e30f, m1=-1e30f, ls0=0.f, ls1=0.f;

  ushort* pt = ptile[wu];
  const ushort* kbh = khi + (size_t)b*NPIX*CQ;
  const ushort* kbl = klo + (size_t)b*NPIX*CQ;
  const int kofs_lane = llo*CQ + lhi*8;

  // prologue: stage tile 0
  #pragma unroll
  for (int k=0;k<8;++k)
    gload16(vt + vbase + (uint32_t)(k*8*NPIX), &vtile[0][(wu*64 + k*8)*64]);
  __syncthreads();

  #pragma unroll 1
  for (int tt=0; tt<64; ++tt){
    const int cur = tt & 1;

    // (a) K fragment loads FIRST (so QK's waitcnt leaves staging in flight)
    s16x8 kh[4], kl2[4];
    #pragma unroll
    for (int jt=0;jt<4;++jt){
      int ko = tt*64*CQ + jt*16*CQ + kofs_lane;
      kh[jt]  = *(const s16x8*)(kbh + ko);
      kl2[jt] = *(const s16x8*)(kbl + ko);
    }
    __builtin_amdgcn_sched_barrier(0);
    // (b) issue next V tile staging (vmcnt stays >0 across QK)
    if (tt < 63){
      const uint32_t src = vbase + (uint32_t)((tt+1)*64);
      #pragma unroll
      for (int k=0;k<8;++k)
        gload16(vt + src + (uint32_t)(k*8*NPIX),
                &vtile[cur^1][(wu*64 + k*8)*64]);
    }

    // (c) S^T = K.Q^T, 3-term hi/lo split (err ~1e-4 on logits)
    f32x4 st[2][4];
    #pragma unroll
    for (int rt=0;rt<2;++rt)
      #pragma unroll
      for (int jt=0;jt<4;++jt) st[rt][jt] = (f32x4){0.f,0.f,0.f,0.f};
    __builtin_amdgcn_s_setprio(1);
    #pragma unroll
    for (int jt=0;jt<4;++jt){
      #pragma unroll
      for (int rt=0;rt<2;++rt){
        st[rt][jt] = __builtin_amdgcn_mfma_f32_16x16x32_bf16(kh[jt],  qh[rt],  st[rt][jt], 0,0,0);
        st[rt][jt] = __builtin_amdgcn_mfma_f32_16x16x32_bf16(kl2[jt], qh[rt],  st[rt][jt], 0,0,0);
        st[rt][jt] = __builtin_amdgcn_mfma_f32_16x16x32_bf16(kh[jt],  qlf[rt], st[rt][jt], 0,0,0);
      }
    }
    __builtin_amdgcn_s_setprio(0);

    // (d) online softmax; state (m,ls) per lane-column i=llo, dup over lhi
    float mt0 = st[0][0][0], mt1 = st[1][0][0];
    #pragma unroll
    for (int jt=0;jt<4;++jt)
      #pragma unroll
      for (int r=0;r<4;++r){
        mt0 = fmaxf(mt0, st[0][jt][r]);
        mt1 = fmaxf(mt1, st[1][jt][r]);
      }
    mt0 = fmaxf(mt0, __shfl_xor(mt0, 16)); mt0 = fmaxf(mt0, __shfl_xor(mt0, 32));
    mt1 = fmaxf(mt1, __shfl_xor(mt1, 16)); mt1 = fmaxf(mt1, __shfl_xor(mt1, 32));
    int keep = (mt0 <= m0 + 8.f) && (mt1 <= m1 + 8.f);   // defer-max (T13)
    if (!__all(keep)){
      float n0m = fmaxf(m0, mt0), n1m = fmaxf(m1, mt1);
      float f0 = __expf(m0 - n0m), f1 = __expf(m1 - n1m);
      m0 = n0m; m1 = n1m; ls0 *= f0; ls1 *= f1;
      #pragma unroll
      for (int ct=0;ct<16;++ct){ acc[ct][0] *= f0; acc[ct][1] *= f1; }
    }
    // p = exp(S-m) (<= e^8), pack bf16 into wave-private swizzled P^T tile
    #pragma unroll
    for (int rt=0;rt<2;++rt){
      float mr = rt ? m1 : m0;
      float lacc = 0.f;
      int il = rt*16 + llo;
      #pragma unroll
      for (int jt=0;jt<4;++jt){
        union { ushort u[4]; uint2 v; } pk;
        #pragma unroll
        for (int r=0;r<4;++r){
          float p = __expf(st[rt][jt][r] - mr);
          lacc += p;
          pk.u[r] = f2bf(p);
        }
        int jcb = jt*2 + (lhi>>1);   // logical 8-chunk = j>>3
        int sub = lhi & 1;
        *(uint2*)&pt[il*64 + ((jcb ^ (il&7))<<3) + sub*4] = pk.v;
      }
      if (rt) ls1 += lacc; else ls0 += lacc;
    }
    // (e) PV: out^T += V^T . P^T
    s16x8 pf[2][2];
    #pragma unroll
    for (int it=0; it<2; ++it){
      int il = it*16 + llo;
      #pragma unroll
      for (int jh=0; jh<2; ++jh)
        pf[it][jh] = *(const s16x8*)&pt[il*64 + (((jh*4+lhi) ^ (il&7))<<3)];
    }
    __builtin_amdgcn_s_setprio(1);
    #pragma unroll
    for (int ct=0; ct<16; ++ct){
      int c = ct*16 + llo;
      #pragma unroll
      for (int jh=0; jh<2; ++jh){
        s16x8 vf = *(const s16x8*)&vtile[cur][c*64 + (((jh*4+lhi) ^ (c&7))<<3)];
        acc[ct][0] = __builtin_amdgcn_mfma_f32_16x16x32_bf16(vf, pf[0][jh], acc[ct][0], 0,0,0);
        acc[ct][1] = __builtin_amdgcn_mfma_f32_16x16x32_bf16(vf, pf[1][jh], acc[ct][1], 0,0,0);
      }
    }
    __builtin_amdgcn_s_setprio(0);
    __syncthreads();   // drains staging vmcnt; tile tt+1 ready
  }

  // ---- epilogue: normalize, gamma*out + x, coalesced along i ----
  ls0 += __shfl_xor(ls0,16); ls0 += __shfl_xor(ls0,32);
  ls1 += __shfl_xor(ls1,16); ls1 += __shfl_xor(ls1,32);
  float rinv0 = 1.f/ls0, rinv1 = 1.f/ls1;
  float g = gamma[0];
  #pragma unroll
  for (int ct=0; ct<16; ++ct){
    #pragma unroll
    for (int it=0; it<2; ++it){
      float ri = it ? rinv1 : rinv0;
      #pragma unroll
      for (int r=0;r<4;++r){
        int c  = ct*16 + lhi*4 + r;       // D row = c-in-tile
        int ii = i0 + wu*32 + it*16 + llo; // D col = i
        size_t o = ((size_t)b*CH + c)*NPIX + ii;
        out[o] = g * acc[ct][it][r] * ri + x[o];
      }
    }
  }
}

extern "C" void kernel_launch(void* const* d_in, const int* in_sizes, int n_in,
                              void* d_out, int out_size, void* d_ws, size_t ws_size,
                              hipStream_t stream)
{
  (void)in_sizes; (void)n_in; (void)out_size; (void)ws_size;
  const float* x     = (const float*)d_in[0];
  const float* Wq    = (const float*)d_in[1];
  const float* bq    = (const float*)d_in[2];
  const float* Wk    = (const float*)d_in[3];
  const float* bk    = (const float*)d_in[4];
  const float* Wv    = (const float*)d_in[5];
  const float* bv    = (const float*)d_in[6];
  const float* gamma = (const float*)d_in[7];
  float* out = (float*)d_out;

  ushort* ws = (ushort*)d_ws;
  const size_t qk_elems = (size_t)BATCH*NPIX*CQ;    // 4 MB each
  ushort* qhi = ws;
  ushort* qlo = qhi + qk_elems;
  ushort* khi = qlo + qk_elems;
  ushort* klo = khi + qk_elems;
  ushort* vt  = klo + qk_elems;                     // 33.5 MB

  dim3 gp(64, BATCH);
  proj_kernel<<<gp, dim3(256), 0, stream>>>(x, Wq, bq, Wk, bk, Wv, bv,
                                            qhi, qlo, khi, klo, vt);
  dim3 ga(32, BATCH);
  attn_kernel<<<ga, dim3(256), 0, stream>>>(qhi, qlo, khi, klo, vt, x, gamma, out);
}

// Round 6
// 365.807 us; speedup vs baseline: 1.6489x; 1.6489x over previous
//
#include <hip/hip_runtime.h>
#include <stdint.h>

#define BATCH 16
#define CH    256
#define CQ    32
#define NPIX  4096
#define WROWS 320

typedef float f32x4 __attribute__((ext_vector_type(4)));
typedef short s16x8 __attribute__((ext_vector_type(8)));

__device__ __forceinline__ ushort f2bf(float f){
  union { float f; uint32_t u; } a; a.f = f;
  uint32_t r = a.u + 0x7FFFu + ((a.u >> 16) & 1u);
  return (ushort)(r >> 16);
}
__device__ __forceinline__ float bf2f(ushort h){
  union { float f; uint32_t u; } a; a.u = ((uint32_t)h) << 16; return a.f;
}
__device__ __forceinline__ void gload16(const void* g, void* l){
  __builtin_amdgcn_global_load_lds(
      (const __attribute__((address_space(1))) uint32_t*)g,
      (__attribute__((address_space(3))) uint32_t*)l, 16, 0, 0);
}

// ------------------------------------------------------------------
// prep_w: W (fp32) -> bf16 hi/lo planes [320][256].
// rows 0..31 = Wq, 32..63 = Wk, 64..319 = Wv.
// ------------------------------------------------------------------
__global__ __launch_bounds__(256) void prep_w(
    const float* __restrict__ Wq, const float* __restrict__ Wk,
    const float* __restrict__ Wv,
    ushort* __restrict__ whi, ushort* __restrict__ wlo)
{
  int idx = blockIdx.x*256 + threadIdx.x;        // 0..81919
  int r = idx >> 8;
  float f = (r < 32) ? Wq[idx] : (r < 64) ? Wk[idx - 32*CH] : Wv[idx - 64*CH];
  ushort h = f2bf(f);
  whi[idx] = h;
  wlo[idx] = f2bf(f - bf2f(h));
}

// ------------------------------------------------------------------
// proj_mfma: q/k/v = W @ x + b as bf16 MFMA GEMM (3-term hi/lo split).
// Block = [320 co x 64 n] per batch. Wave w owns co [80w, 80w+80).
// x staged fp32 in LDS [n][c] with 16B-chunk swizzle phys=chunk^(n&7):
// conflict-free b128 stores AND frag reads (8-slot/wave minimum).
// ------------------------------------------------------------------
__global__ __launch_bounds__(256,2) void proj_mfma(
    const float* __restrict__ x,
    const ushort* __restrict__ whi, const ushort* __restrict__ wlo,
    const float* __restrict__ bq, const float* __restrict__ bk,
    const float* __restrict__ bv,
    ushort* __restrict__ qhi, ushort* __restrict__ qlo,
    ushort* __restrict__ khi, ushort* __restrict__ klo,
    ushort* __restrict__ vt)
{
  __shared__ __align__(16) float xT[64*256];     // 64 KB
  const int b  = blockIdx.y;
  const int n0 = blockIdx.x * 64;
  const int t  = threadIdx.x;
  const int wu = __builtin_amdgcn_readfirstlane(t >> 6);
  const int l  = t & 63;
  const int g  = l >> 4, li = l & 15, lsw = l & 7;

  // ---- stage x[c][n0..n0+64) -> xT[n-local=l][c] fp32, swizzled ----
  {
    const float* xb = x + ((size_t)b*CH)*NPIX + n0 + l;
    #pragma unroll
    for (int cq = 0; cq < 16; ++cq) {
      int c4 = wu*64 + cq*4;
      f32x4 v;
      v[0] = xb[(size_t)(c4+0)*NPIX];
      v[1] = xb[(size_t)(c4+1)*NPIX];
      v[2] = xb[(size_t)(c4+2)*NPIX];
      v[3] = xb[(size_t)(c4+3)*NPIX];
      int phys = (c4 >> 2) ^ lsw;
      *(f32x4*)&xT[l*256 + phys*4] = v;
    }
  }
  __syncthreads();

  f32x4 acc[5][4];
  #pragma unroll
  for (int ct=0;ct<5;++ct)
    #pragma unroll
    for (int nt=0;nt<4;++nt) acc[ct][nt] = (f32x4){0.f,0.f,0.f,0.f};

  #pragma unroll 1
  for (int ks = 0; ks < 8; ++ks) {
    s16x8 wh[5], wl[5];
    #pragma unroll
    for (int ct = 0; ct < 5; ++ct) {
      size_t off = (size_t)(wu*80 + ct*16 + li)*CH + ks*32 + g*8;
      wh[ct] = *(const s16x8*)(whi + off);
      wl[ct] = *(const s16x8*)(wlo + off);
    }
    s16x8 xh[4], xl[4];
    #pragma unroll
    for (int nt = 0; nt < 4; ++nt) {
      int row = nt*16 + li;
      int ch0 = ks*8 + 2*g;
      f32x4 a0 = *(const f32x4*)&xT[row*256 + ((ch0    ) ^ (li&7))*4];
      f32x4 a1 = *(const f32x4*)&xT[row*256 + ((ch0 + 1) ^ (li&7))*4];
      float fv[8] = {a0[0],a0[1],a0[2],a0[3],a1[0],a1[1],a1[2],a1[3]};
      union { ushort u[8]; s16x8 v; } ph, pl;
      #pragma unroll
      for (int e=0;e<8;++e){
        ushort h = f2bf(fv[e]); ph.u[e] = h; pl.u[e] = f2bf(fv[e] - bf2f(h));
      }
      xh[nt] = ph.v; xl[nt] = pl.v;
    }
    #pragma unroll
    for (int ct=0;ct<5;++ct)
      #pragma unroll
      for (int nt=0;nt<4;++nt){
        acc[ct][nt] = __builtin_amdgcn_mfma_f32_16x16x32_bf16(wh[ct], xh[nt], acc[ct][nt], 0,0,0);
        acc[ct][nt] = __builtin_amdgcn_mfma_f32_16x16x32_bf16(wh[ct], xl[nt], acc[ct][nt], 0,0,0);
        acc[ct][nt] = __builtin_amdgcn_mfma_f32_16x16x32_bf16(wl[ct], xh[nt], acc[ct][nt], 0,0,0);
      }
  }

  const int rsub = g*4;
  #pragma unroll
  for (int ct = 0; ct < 5; ++ct) {
    const int cog = wu*80 + ct*16;
    if (cog < 64) {
      const float*  bias = (cog < 32) ? bq  : bk;
      ushort*       dhi  = (cog < 32) ? qhi : khi;
      ushort*       dlo  = (cog < 32) ? qlo : klo;
      const int cb = (cog & 31) + rsub;
      float4 bi = *(const float4*)(bias + cb);
      #pragma unroll
      for (int nt = 0; nt < 4; ++nt) {
        int n = n0 + nt*16 + li;
        union { ushort u[4]; uint2 v; } ph, pl;
        #pragma unroll
        for (int r = 0; r < 4; ++r) {
          float val = acc[ct][nt][r] + ((const float*)&bi)[r];
          ushort h = f2bf(val);
          ph.u[r] = h; pl.u[r] = f2bf(val - bf2f(h));
        }
        size_t base = ((size_t)b*NPIX + n)*CQ + cb;
        *(uint2*)(dhi + base) = ph.v;
        *(uint2*)(dlo + base) = pl.v;
      }
    } else {
      const int vr = cog - 64 + rsub;
      float4 bi = *(const float4*)(bv + vr);
      #pragma unroll
      for (int nt = 0; nt < 4; ++nt) {
        int n = n0 + nt*16 + li;
        #pragma unroll
        for (int r = 0; r < 4; ++r)
          vt[((size_t)b*CH + vr + r)*NPIX + n] =
              f2bf(acc[ct][nt][r] + ((const float*)&bi)[r]);
      }
    }
  }
}

// ------------------------------------------------------------------
// Fused flash attention + residual. (UNCHANGED from round-3 source.)
// ------------------------------------------------------------------
__global__ __launch_bounds__(256,2) void attn_kernel(
    const ushort* __restrict__ qhi, const ushort* __restrict__ qlo,
    const ushort* __restrict__ khi, const ushort* __restrict__ klo,
    const ushort* __restrict__ vt,  const float* __restrict__ x,
    const float* __restrict__ gamma, float* __restrict__ out)
{
  __shared__ __align__(16) ushort vtile[2][CH*64];
  __shared__ __align__(16) ushort ptile[4][32*64];

  const int flat = blockIdx.x + (int)gridDim.x * blockIdx.y;
  const int nf   = (flat & 7)*64 + (flat >> 3);
  const int b    = nf >> 5;
  const int i0   = (nf & 31) << 7;

  const int t   = threadIdx.x;
  const int wu  = __builtin_amdgcn_readfirstlane(t >> 6);
  const int l   = t & 63, lhi = l >> 4, llo = l & 15;

  const int crow = l >> 3;
  const int jsw  = ((l & 7) ^ crow) * 8;
  const uint32_t vbase = (uint32_t)((b*CH + wu*64 + crow)*NPIX) + (uint32_t)jsw;

  s16x8 qh[2], qlf[2];
  #pragma unroll
  for (int rt=0; rt<2; ++rt){
    size_t off = ((size_t)b*NPIX + i0 + wu*32 + rt*16 + llo)*CQ + lhi*8;
    qh[rt]  = *(const s16x8*)(qhi + off);
    qlf[rt] = *(const s16x8*)(qlo + off);
  }

  f32x4 acc[16][2];
  #pragma unroll
  for (int ct=0;ct<16;++ct){
    acc[ct][0] = (f32x4){0.f,0.f,0.f,0.f};
    acc[ct][1] = (f32x4){0.f,0.f,0.f,0.f};
  }
  float m0=-1e30f, m1=-1e30f, ls0=0.f, ls1=0.f;

  ushort* pt = ptile[wu];
  const ushort* kbh = khi + (size_t)b*NPIX*CQ;
  const ushort* kbl = klo + (size_t)b*NPIX*CQ;
  const int kofs_lane = llo*CQ + lhi*8;

  #pragma unroll
  for (int k=0;k<8;++k)
    gload16(vt + vbase + (uint32_t)(k*8*NPIX), &vtile[0][(wu*64 + k*8)*64]);
  __syncthreads();

  #pragma unroll 1
  for (int tt=0; tt<64; ++tt){
    const int cur = tt & 1;

    s16x8 kh[4], kl2[4];
    #pragma unroll
    for (int jt=0;jt<4;++jt){
      int ko = tt*64*CQ + jt*16*CQ + kofs_lane;
      kh[jt]  = *(const s16x8*)(kbh + ko);
      kl2[jt] = *(const s16x8*)(kbl + ko);
    }
    __builtin_amdgcn_sched_barrier(0);
    if (tt < 63){
      const uint32_t src = vbase + (uint32_t)((tt+1)*64);
      #pragma unroll
      for (int k=0;k<8;++k)
        gload16(vt + src + (uint32_t)(k*8*NPIX),
                &vtile[cur^1][(wu*64 + k*8)*64]);
    }

    f32x4 st[2][4];
    #pragma unroll
    for (int rt=0;rt<2;++rt)
      #pragma unroll
      for (int jt=0;jt<4;++jt) st[rt][jt] = (f32x4){0.f,0.f,0.f,0.f};
    __builtin_amdgcn_s_setprio(1);
    #pragma unroll
    for (int jt=0;jt<4;++jt){
      #pragma unroll
      for (int rt=0;rt<2;++rt){
        st[rt][jt] = __builtin_amdgcn_mfma_f32_16x16x32_bf16(kh[jt],  qh[rt],  st[rt][jt], 0,0,0);
        st[rt][jt] = __builtin_amdgcn_mfma_f32_16x16x32_bf16(kl2[jt], qh[rt],  st[rt][jt], 0,0,0);
        st[rt][jt] = __builtin_amdgcn_mfma_f32_16x16x32_bf16(kh[jt],  qlf[rt], st[rt][jt], 0,0,0);
      }
    }
    __builtin_amdgcn_s_setprio(0);

    float mt0 = st[0][0][0], mt1 = st[1][0][0];
    #pragma unroll
    for (int jt=0;jt<4;++jt)
      #pragma unroll
      for (int r=0;r<4;++r){
        mt0 = fmaxf(mt0, st[0][jt][r]);
        mt1 = fmaxf(mt1, st[1][jt][r]);
      }
    mt0 = fmaxf(mt0, __shfl_xor(mt0, 16)); mt0 = fmaxf(mt0, __shfl_xor(mt0, 32));
    mt1 = fmaxf(mt1, __shfl_xor(mt1, 16)); mt1 = fmaxf(mt1, __shfl_xor(mt1, 32));
    int keep = (mt0 <= m0 + 8.f) && (mt1 <= m1 + 8.f);
    if (!__all(keep)){
      float n0m = fmaxf(m0, mt0), n1m = fmaxf(m1, mt1);
      float f0 = __expf(m0 - n0m), f1 = __expf(m1 - n1m);
      m0 = n0m; m1 = n1m; ls0 *= f0; ls1 *= f1;
      #pragma unroll
      for (int ct=0;ct<16;++ct){ acc[ct][0] *= f0; acc[ct][1] *= f1; }
    }
    #pragma unroll
    for (int rt=0;rt<2;++rt){
      float mr = rt ? m1 : m0;
      float lacc = 0.f;
      int il = rt*16 + llo;
      #pragma unroll
      for (int jt=0;jt<4;++jt){
        union { ushort u[4]; uint2 v; } pk;
        #pragma unroll
        for (int r=0;r<4;++r){
          float p = __expf(st[rt][jt][r] - mr);
          lacc += p;
          pk.u[r] = f2bf(p);
        }
        int jcb = jt*2 + (lhi>>1);
        int sub = lhi & 1;
        *(uint2*)&pt[il*64 + ((jcb ^ (il&7))<<3) + sub*4] = pk.v;
      }
      if (rt) ls1 += lacc; else ls0 += lacc;
    }
    s16x8 pf[2][2];
    #pragma unroll
    for (int it=0; it<2; ++it){
      int il = it*16 + llo;
      #pragma unroll
      for (int jh=0; jh<2; ++jh)
        pf[it][jh] = *(const s16x8*)&pt[il*64 + (((jh*4+lhi) ^ (il&7))<<3)];
    }
    __builtin_amdgcn_s_setprio(1);
    #pragma unroll
    for (int ct=0; ct<16; ++ct){
      int c = ct*16 + llo;
      #pragma unroll
      for (int jh=0; jh<2; ++jh){
        s16x8 vf = *(const s16x8*)&vtile[cur][c*64 + (((jh*4+lhi) ^ (c&7))<<3)];
        acc[ct][0] = __builtin_amdgcn_mfma_f32_16x16x32_bf16(vf, pf[0][jh], acc[ct][0], 0,0,0);
        acc[ct][1] = __builtin_amdgcn_mfma_f32_16x16x32_bf16(vf, pf[1][jh], acc[ct][1], 0,0,0);
      }
    }
    __builtin_amdgcn_s_setprio(0);
    __syncthreads();
  }

  ls0 += __shfl_xor(ls0,16); ls0 += __shfl_xor(ls0,32);
  ls1 += __shfl_xor(ls1,16); ls1 += __shfl_xor(ls1,32);
  float rinv0 = 1.f/ls0, rinv1 = 1.f/ls1;
  float gmv = gamma[0];
  #pragma unroll
  for (int ct=0; ct<16; ++ct){
    #pragma unroll
    for (int it=0; it<2; ++it){
      float ri = it ? rinv1 : rinv0;
      #pragma unroll
      for (int r=0;r<4;++r){
        int c  = ct*16 + lhi*4 + r;
        int ii = i0 + wu*32 + it*16 + llo;
        size_t o = ((size_t)b*CH + c)*NPIX + ii;
        out[o] = gmv * acc[ct][it][r] * ri + x[o];
      }
    }
  }
}

extern "C" void kernel_launch(void* const* d_in, const int* in_sizes, int n_in,
                              void* d_out, int out_size, void* d_ws, size_t ws_size,
                              hipStream_t stream)
{
  (void)in_sizes; (void)n_in; (void)out_size; (void)ws_size;
  const float* x     = (const float*)d_in[0];
  const float* Wq    = (const float*)d_in[1];
  const float* bq    = (const float*)d_in[2];
  const float* Wk    = (const float*)d_in[3];
  const float* bk    = (const float*)d_in[4];
  const float* Wv    = (const float*)d_in[5];
  const float* bv    = (const float*)d_in[6];
  const float* gamma = (const float*)d_in[7];
  float* out = (float*)d_out;

  ushort* ws = (ushort*)d_ws;
  const size_t qk_elems = (size_t)BATCH*NPIX*CQ;
  ushort* qhi = ws;
  ushort* qlo = qhi + qk_elems;
  ushort* khi = qlo + qk_elems;
  ushort* klo = khi + qk_elems;
  ushort* vt  = klo + qk_elems;
  ushort* whi = vt  + (size_t)BATCH*CH*NPIX;
  ushort* wlo = whi + (size_t)WROWS*CH;

  prep_w<<<dim3(WROWS), dim3(256), 0, stream>>>(Wq, Wk, Wv, whi, wlo);
  dim3 gp(64, BATCH);
  proj_mfma<<<gp, dim3(256), 0, stream>>>(x, whi, wlo, bq, bk, bv,
                                          qhi, qlo, khi, klo, vt);
  dim3 ga(32, BATCH);
  attn_kernel<<<ga, dim3(256), 0, stream>>>(qhi, qlo, khi, klo, vt, x, gamma, out);
}